// Round 10
// baseline (251.897 us; speedup 1.0000x reference)
//
#include <hip/hip_runtime.h>

#define N 2048
#define NT 256
#define EL 8            // elements per thread
#define HEIGHTF 0.1f
#define PROMF 0.05f
#define LVLS 8          // sparse-table levels: windows 2,4,...,256

// ===================== measurement probes =====================
// DEPTH=1: load+normalize+candidates+gather; 2:+suppression; 3:+tables; 4:+prominence
template<int DEPTH>
__global__ __launch_bounds__(NT)
void probe_kernel(const float* __restrict__ x, float* __restrict__ out, int reps) {
    __shared__ float xs[N];
    __shared__ float actl[16 + N + 24];
    __shared__ unsigned int nk32[3 + NT + 3];
    __shared__ float TMX[LVLS][N];
    __shared__ float TMN[LVLS][N];
    __shared__ float wred[8];
    __shared__ int wtot[4];
    __shared__ unsigned short klist[NT];
    __shared__ unsigned char keepres[N];
    __shared__ int donecnt;

    const int row = blockIdx.x;
    const int t = threadIdx.x;
    const int base = t * EL;
    const float* xr = x + row * (size_t)N;
    const int wv = t >> 6, ln = t & 63;

    for (int rep = 0; rep < reps; ++rep) {
        int z = 0;
        asm volatile("" : "+v"(z));   // opaque per-rep zero: defeats LICM
        __syncthreads();              // close previous rep

        // ---- phase 1: load + min/max + normalize + candidates + gather ----
        float4 Ld0 = ((const float4*)(xr + base + z))[0];
        float4 Ld1 = ((const float4*)(xr + base + z))[1];
        float v0[EL] = {Ld0.x, Ld0.y, Ld0.z, Ld0.w, Ld1.x, Ld1.y, Ld1.z, Ld1.w};
        float mn = v0[0], mx = v0[0];
        #pragma unroll
        for (int e = 1; e < EL; ++e) { mn = fminf(mn, v0[e]); mx = fmaxf(mx, v0[e]); }
        #pragma unroll
        for (int off = 32; off > 0; off >>= 1) {
            mn = fminf(mn, __shfl_xor(mn, off, 64));
            mx = fmaxf(mx, __shfl_xor(mx, off, 64));
        }
        if (ln == 0) { wred[wv] = mn; wred[4 + wv] = mx; }
        if (t < 16) actl[t] = -1e30f;
        if (t < 24) actl[16 + N + t] = -1e30f;
        __syncthreads();
        const float xmin = fminf(fminf(wred[0], wred[1]), fminf(wred[2], wred[3]));
        const float xmax = fmaxf(fmaxf(wred[4], wred[5]), fmaxf(wred[6], wred[7]));
        const float den = (xmax - xmin) + 1e-5f;
        float vn[EL];
        #pragma unroll
        for (int e = 0; e < EL; ++e) {
            vn[e] = (v0[e] - xmin) / den;
            xs[base + e] = vn[e];
        }
        __syncthreads();
        unsigned int undec = 0, kept = 0;
        #pragma unroll
        for (int e = 0; e < EL; ++e) {
            int i = base + e;
            float v = vn[e];
            float lf = (e == 0) ? ((i >= 1) ? xs[i-1] : 3e38f) : vn[e-1];
            float rt = (e == EL-1) ? ((i+1 < N) ? xs[i+1] : 3e38f) : vn[e+1];
            bool c = (i >= 1) && (i <= N-2) && (v > lf) && (v > rt) && (v >= HEIGHTF);
            if (c) undec |= (1u << e);
            actl[16 + i] = c ? v : -1e30f;
        }
        __syncthreads();
        float a[40];
        {
            const float4* ap = (const float4*)(actl + base);
            #pragma unroll
            for (int q = 0; q < 10; ++q) {
                float4 w = ap[q];
                a[4*q+0] = w.x; a[4*q+1] = w.y; a[4*q+2] = w.z; a[4*q+3] = w.w;
            }
        }
        asm volatile("" :: "v"(undec), "v"(a[16]), "v"(a[0]), "v"(a[39]));

        auto compute_wins = [&](unsigned int ud) -> unsigned int {
            float m2v[25], m4v[23], m8v[19];
            #pragma unroll
            for (int s = 0; s < 25; ++s) m2v[s] = fmaxf(a[7+s], a[8+s]);
            #pragma unroll
            for (int s = 0; s < 23; ++s) m4v[s] = fmaxf(m2v[s], m2v[s+2]);
            #pragma unroll
            for (int s = 0; s < 19; ++s) m8v[s] = fmaxf(m4v[s], m4v[s+4]);
            unsigned int wb = 0;
            #pragma unroll
            for (int e = 0; e < EL; ++e) {
                if (ud & (1u << e)) {
                    float v = a[16+e];
                    float wl = fmaxf(m8v[e], a[15+e]);
                    float wr = fmaxf(m8v[10+e], a[25+e]);
                    if (wl < v && wr <= v) wb |= (1u << e);
                }
            }
            return wb;
        };

        if constexpr (DEPTH >= 2) {
            // reset publish state for this rep
            nk32[t] = 0;
            if (t < 6) nk32[NT + t] = 0;
            if (t == 0) donecnt = 0;
            __syncthreads();
            volatile unsigned int* nkv = nk32 + 3;
            volatile int* dcp = (volatile int*)&donecnt;
            unsigned long long lastV = ~0ULL;
            bool counted = false;
            int guard = 0;
            while (true) {
                if (undec) {
                    unsigned long long V = 0;
                    #pragma unroll
                    for (int q = 0; q < 7; ++q)
                        V |= ((unsigned long long)(nkv[t - 3 + q] & 0xFFu)) << (8 * q);
                    V <<= 1;
                    if (V != lastV) {
                        lastV = V;
                        #pragma unroll
                        for (int s = 0; s < 40; ++s)
                            if ((V >> s) & 0x7FFFFULL) a[s] = -1e30f;
                        #pragma unroll
                        for (int e = 0; e < EL; ++e)
                            if (undec & (1u << e))
                                if ((V >> (16 + e)) & 0x7FFFFULL) undec &= ~(1u << e);
                        if (undec) {
                            unsigned int wb = compute_wins(undec);
                            if (wb) {
                                kept |= wb;
                                undec = 0;
                                nkv[t] = kept;
                            }
                        }
                    } else {
                        __builtin_amdgcn_s_sleep(1);
                    }
                }
                if (!undec && !counted) {
                    nkv[t] = kept;
                    __threadfence_block();
                    atomicAdd(&donecnt, 1);
                    counted = true;
                }
                if (*dcp >= NT) break;
                if (counted) __builtin_amdgcn_s_sleep(2);
                if (++guard > 65536) break;
            }
            __syncthreads();
            asm volatile("" :: "v"(kept));
        }

        int ktot = 0;
        if constexpr (DEPTH >= 3) {
            float cx[EL], cn[EL];
            #pragma unroll
            for (int j = 0; j < EL; ++j) {
                int i = t + j * NT;
                float a0 = xs[i];
                bool inb = (i + 1 < N);
                float nb = inb ? xs[i + 1] : 0.0f;
                cx[j] = fmaxf(a0, inb ? nb : -3e38f);
                cn[j] = fminf(a0, inb ? nb : 3e38f);
                TMX[0][i] = cx[j];
                TMN[0][i] = cn[j];
            }
            int myc = __popc(kept);
            int pre = myc;
            #pragma unroll
            for (int off = 1; off < 64; off <<= 1) {
                int up = __shfl_up(pre, off, 64);
                if (ln >= off) pre += up;
            }
            if (ln == 63) wtot[wv] = pre;
            #pragma unroll
            for (int e = 0; e < EL; ++e) keepres[base + e] = 0;
            __syncthreads();
            {
                int woff = 0;
                #pragma unroll
                for (int w = 0; w < 4; ++w) woff += (w < wv) ? wtot[w] : 0;
                int slot = woff + pre - myc;
                #pragma unroll
                for (int e = 0; e < EL; ++e)
                    if (kept & (1u << e)) klist[slot++] = (unsigned short)(base + e);
            }
            ktot = wtot[0] + wtot[1] + wtot[2] + wtot[3];
            #pragma unroll
            for (int pp = 0; pp < 3; ++pp) {
                const int Lv = 1 + 2 * pp;
                const int h = 1 << Lv;
                #pragma unroll
                for (int j = 0; j < EL; ++j) {
                    int i = t + j * NT;
                    float x1 = (i +   h < N) ? TMX[Lv-1][i+  h] : -3e38f;
                    float x2 = (i + 2*h < N) ? TMX[Lv-1][i+2*h] : -3e38f;
                    float x3 = (i + 3*h < N) ? TMX[Lv-1][i+3*h] : -3e38f;
                    float n1 = (i +   h < N) ? TMN[Lv-1][i+  h] : 3e38f;
                    float n2 = (i + 2*h < N) ? TMN[Lv-1][i+2*h] : 3e38f;
                    float n3 = (i + 3*h < N) ? TMN[Lv-1][i+3*h] : 3e38f;
                    float tx = fmaxf(cx[j], x1), tn = fminf(cn[j], n1);
                    TMX[Lv][i] = tx;  TMN[Lv][i] = tn;
                    cx[j] = fmaxf(tx, fmaxf(x2, x3));
                    cn[j] = fminf(tn, fminf(n2, n3));
                    TMX[Lv+1][i] = cx[j];  TMN[Lv+1][i] = cn[j];
                }
                __syncthreads();
            }
            {
                const int h = 128;
                #pragma unroll
                for (int j = 0; j < EL; ++j) {
                    int i = t + j * NT;
                    float x1 = (i + h < N) ? TMX[6][i+h] : -3e38f;
                    float n1 = (i + h < N) ? TMN[6][i+h] : 3e38f;
                    cx[j] = fmaxf(cx[j], x1);
                    cn[j] = fminf(cn[j], n1);
                    TMX[7][i] = cx[j];  TMN[7][i] = cn[j];
                }
                __syncthreads();
            }
            float live3 = TMX[7][t] + TMN[7][t + NT] + (float)ktot;
            asm volatile("" :: "v"(live3));
        }

        if constexpr (DEPTH >= 4) {
            if (t < ktot) {
                const int i = klist[t];
                const float v = xs[i];
                const float* TX0 = &TMX[0][0];
                const float* TN0 = &TMN[0][0];
                int Lph = 0, Lp = i - 1, Lk = 0, Ls = 0;
                float Lm = v;
                if (Lp < 0) Lph = 2;
                int Rph = 0, Rp = i + 1, Rk = 0;
                float Rm = v;
                if (Rp >= N) Rph = 2;
                while (Lph != 2 || Rph != 2) {
                    int lLev = 0, lIdx = 0, rLev = 0, rIdx = 0, Lrs = 0;
                    if (Lph == 0) {
                        int len = Lp + 1;
                        Lk = (len >= (1 << LVLS)) ? LVLS : (31 - __clz(len));
                        Ls = Lp + 1 - (1 << Lk);
                        lLev = Lk - 1; lIdx = Ls;
                    } else if (Lph == 1) {
                        Lrs = Ls + (1 << (Lk - 1));
                        lLev = Lk - 2; lIdx = Lrs;
                    }
                    if (Rph == 0) {
                        int len = N - Rp;
                        Rk = (len >= (1 << LVLS)) ? LVLS : (31 - __clz(len));
                        rLev = Rk - 1; rIdx = Rp;
                    } else if (Rph == 1) {
                        rLev = Rk - 2; rIdx = Rp;
                    }
                    float lx = 0.0f, lnv = 0.0f, rx = 0.0f, rnv = 0.0f;
                    if (Lph != 2) {
                        const float* bX = (lLev < 0) ? xs : (TX0 + lLev * N);
                        const float* bN = (lLev < 0) ? xs : (TN0 + lLev * N);
                        lx = bX[lIdx]; lnv = bN[lIdx];
                    }
                    if (Rph != 2) {
                        const float* bX = (rLev < 0) ? xs : (TX0 + rLev * N);
                        const float* bN = (rLev < 0) ? xs : (TN0 + rLev * N);
                        rx = bX[rIdx]; rnv = bN[rIdx];
                    }
                    if (Lph == 0) {
                        if (lx > v) Lph = (Lk == 0) ? 2 : 1;
                        else { Lm = fminf(Lm, lnv); Lp = Ls - 1; if (Lp < 0) Lph = 2; }
                    } else if (Lph == 1) {
                        if (lx > v) Ls = Lrs; else Lm = fminf(Lm, lnv);
                        if (--Lk == 0) Lph = 2;
                    }
                    if (Rph == 0) {
                        if (rx > v) Rph = (Rk == 0) ? 2 : 1;
                        else { Rm = fminf(Rm, rnv); Rp += (1 << Rk); if (Rp >= N) Rph = 2; }
                    } else if (Rph == 1) {
                        if (!(rx > v)) { Rm = fminf(Rm, rnv); Rp += (1 << (Rk - 1)); }
                        if (--Rk == 0) Rph = 2;
                    }
                }
                if (v - fmaxf(Lm, Rm) >= PROMF) keepres[i] = 1;
            }
            __syncthreads();
            float live4 = (float)keepres[base] + (float)keepres[base + 7];
            asm volatile("" :: "v"(live4));
        }
    }
}

// ===================== real kernel (R9, verified) =====================
__global__ __launch_bounds__(NT)
void peak_kernel(const float* __restrict__ x, float* __restrict__ out) {
    __shared__ float xs[N];
    __shared__ float actl[16 + N + 24];
    __shared__ unsigned int nk32[3 + NT + 3];
    __shared__ float TMX[LVLS][N];
    __shared__ float TMN[LVLS][N];
    __shared__ float wred[8];
    __shared__ int wtot[4];
    __shared__ unsigned short klist[NT];
    __shared__ unsigned char keepres[N];
    __shared__ int donecnt;

    const int row = blockIdx.x;
    const int t = threadIdx.x;
    const int base = t * EL;
    const float* xr = x + row * (size_t)N;
    const int wv = t >> 6, ln = t & 63;

    float4 Ld0 = ((const float4*)(xr + base))[0];
    float4 Ld1 = ((const float4*)(xr + base))[1];
    float v0[EL] = {Ld0.x, Ld0.y, Ld0.z, Ld0.w, Ld1.x, Ld1.y, Ld1.z, Ld1.w};
    float mn = v0[0], mx = v0[0];
    #pragma unroll
    for (int e = 1; e < EL; ++e) { mn = fminf(mn, v0[e]); mx = fmaxf(mx, v0[e]); }
    #pragma unroll
    for (int off = 32; off > 0; off >>= 1) {
        mn = fminf(mn, __shfl_xor(mn, off, 64));
        mx = fmaxf(mx, __shfl_xor(mx, off, 64));
    }
    if (ln == 0) { wred[wv] = mn; wred[4 + wv] = mx; }
    nk32[t] = 0;
    if (t < 6) nk32[NT + t] = 0;
    if (t == 0) donecnt = 0;
    if (t < 16) actl[t] = -1e30f;
    if (t < 24) actl[16 + N + t] = -1e30f;
    __syncthreads();

    const float xmin = fminf(fminf(wred[0], wred[1]), fminf(wred[2], wred[3]));
    const float xmax = fmaxf(fmaxf(wred[4], wred[5]), fmaxf(wred[6], wred[7]));
    const float den = (xmax - xmin) + 1e-5f;
    float vn[EL];
    #pragma unroll
    for (int e = 0; e < EL; ++e) {
        vn[e] = (v0[e] - xmin) / den;
        xs[base + e] = vn[e];
    }
    __syncthreads();

    unsigned int undec = 0, kept = 0;
    #pragma unroll
    for (int e = 0; e < EL; ++e) {
        int i = base + e;
        float v = vn[e];
        float lf = (e == 0) ? ((i >= 1) ? xs[i-1] : 3e38f) : vn[e-1];
        float rt = (e == EL-1) ? ((i+1 < N) ? xs[i+1] : 3e38f) : vn[e+1];
        bool c = (i >= 1) && (i <= N-2) && (v > lf) && (v > rt) && (v >= HEIGHTF);
        if (c) undec |= (1u << e);
        actl[16 + i] = c ? v : -1e30f;
    }
    __syncthreads();

    float a[40];
    {
        const float4* ap = (const float4*)(actl + base);
        #pragma unroll
        for (int q = 0; q < 10; ++q) {
            float4 w = ap[q];
            a[4*q+0] = w.x; a[4*q+1] = w.y; a[4*q+2] = w.z; a[4*q+3] = w.w;
        }
    }

    auto compute_wins = [&](unsigned int ud) -> unsigned int {
        float m2v[25], m4v[23], m8v[19];
        #pragma unroll
        for (int s = 0; s < 25; ++s) m2v[s] = fmaxf(a[7+s], a[8+s]);
        #pragma unroll
        for (int s = 0; s < 23; ++s) m4v[s] = fmaxf(m2v[s], m2v[s+2]);
        #pragma unroll
        for (int s = 0; s < 19; ++s) m8v[s] = fmaxf(m4v[s], m4v[s+4]);
        unsigned int wb = 0;
        #pragma unroll
        for (int e = 0; e < EL; ++e) {
            if (ud & (1u << e)) {
                float v = a[16+e];
                float wl = fmaxf(m8v[e], a[15+e]);
                float wr = fmaxf(m8v[10+e], a[25+e]);
                if (wl < v && wr <= v) wb |= (1u << e);
            }
        }
        return wb;
    };

    {
        volatile unsigned int* nkv = nk32 + 3;
        volatile int* dcp = (volatile int*)&donecnt;
        unsigned long long lastV = ~0ULL;
        bool counted = false;
        int guard = 0;
        while (true) {
            if (undec) {
                unsigned long long V = 0;
                #pragma unroll
                for (int q = 0; q < 7; ++q)
                    V |= ((unsigned long long)(nkv[t - 3 + q] & 0xFFu)) << (8 * q);
                V <<= 1;
                if (V != lastV) {
                    lastV = V;
                    #pragma unroll
                    for (int s = 0; s < 40; ++s)
                        if ((V >> s) & 0x7FFFFULL) a[s] = -1e30f;
                    #pragma unroll
                    for (int e = 0; e < EL; ++e)
                        if (undec & (1u << e))
                            if ((V >> (16 + e)) & 0x7FFFFULL) undec &= ~(1u << e);
                    if (undec) {
                        unsigned int wb = compute_wins(undec);
                        if (wb) {
                            kept |= wb;
                            undec = 0;
                            nkv[t] = kept;
                        }
                    }
                } else {
                    __builtin_amdgcn_s_sleep(1);
                }
            }
            if (!undec && !counted) {
                nkv[t] = kept;
                __threadfence_block();
                atomicAdd(&donecnt, 1);
                counted = true;
            }
            if (*dcp >= NT) break;
            if (counted) __builtin_amdgcn_s_sleep(2);
            if (++guard > 65536) break;
        }
    }
    __syncthreads();

    float cx[EL], cn[EL];
    #pragma unroll
    for (int j = 0; j < EL; ++j) {
        int i = t + j * NT;
        float a0 = xs[i];
        bool inb = (i + 1 < N);
        float nb = inb ? xs[i + 1] : 0.0f;
        cx[j] = fmaxf(a0, inb ? nb : -3e38f);
        cn[j] = fminf(a0, inb ? nb : 3e38f);
        TMX[0][i] = cx[j];
        TMN[0][i] = cn[j];
    }
    int myc = __popc(kept);
    int pre = myc;
    #pragma unroll
    for (int off = 1; off < 64; off <<= 1) {
        int up = __shfl_up(pre, off, 64);
        if (ln >= off) pre += up;
    }
    if (ln == 63) wtot[wv] = pre;
    #pragma unroll
    for (int e = 0; e < EL; ++e) keepres[base + e] = 0;
    __syncthreads();

    {
        int woff = 0;
        #pragma unroll
        for (int w = 0; w < 4; ++w) woff += (w < wv) ? wtot[w] : 0;
        int slot = woff + pre - myc;
        #pragma unroll
        for (int e = 0; e < EL; ++e)
            if (kept & (1u << e)) klist[slot++] = (unsigned short)(base + e);
    }
    const int ktot = wtot[0] + wtot[1] + wtot[2] + wtot[3];
    #pragma unroll
    for (int pp = 0; pp < 3; ++pp) {
        const int Lv = 1 + 2 * pp;
        const int h = 1 << Lv;
        #pragma unroll
        for (int j = 0; j < EL; ++j) {
            int i = t + j * NT;
            float x1 = (i +   h < N) ? TMX[Lv-1][i+  h] : -3e38f;
            float x2 = (i + 2*h < N) ? TMX[Lv-1][i+2*h] : -3e38f;
            float x3 = (i + 3*h < N) ? TMX[Lv-1][i+3*h] : -3e38f;
            float n1 = (i +   h < N) ? TMN[Lv-1][i+  h] : 3e38f;
            float n2 = (i + 2*h < N) ? TMN[Lv-1][i+2*h] : 3e38f;
            float n3 = (i + 3*h < N) ? TMN[Lv-1][i+3*h] : 3e38f;
            float tx = fmaxf(cx[j], x1), tn = fminf(cn[j], n1);
            TMX[Lv][i] = tx;  TMN[Lv][i] = tn;
            cx[j] = fmaxf(tx, fmaxf(x2, x3));
            cn[j] = fminf(tn, fminf(n2, n3));
            TMX[Lv+1][i] = cx[j];  TMN[Lv+1][i] = cn[j];
        }
        __syncthreads();
    }
    {
        const int h = 128;
        #pragma unroll
        for (int j = 0; j < EL; ++j) {
            int i = t + j * NT;
            float x1 = (i + h < N) ? TMX[6][i+h] : -3e38f;
            float n1 = (i + h < N) ? TMN[6][i+h] : 3e38f;
            cx[j] = fmaxf(cx[j], x1);
            cn[j] = fminf(cn[j], n1);
            TMX[7][i] = cx[j];  TMN[7][i] = cn[j];
        }
        __syncthreads();
    }

    if (t < ktot) {
        const int i = klist[t];
        const float v = xs[i];
        const float* TX0 = &TMX[0][0];
        const float* TN0 = &TMN[0][0];
        int Lph = 0, Lp = i - 1, Lk = 0, Ls = 0;
        float Lm = v;
        if (Lp < 0) Lph = 2;
        int Rph = 0, Rp = i + 1, Rk = 0;
        float Rm = v;
        if (Rp >= N) Rph = 2;
        while (Lph != 2 || Rph != 2) {
            int lLev = 0, lIdx = 0, rLev = 0, rIdx = 0, Lrs = 0;
            if (Lph == 0) {
                int len = Lp + 1;
                Lk = (len >= (1 << LVLS)) ? LVLS : (31 - __clz(len));
                Ls = Lp + 1 - (1 << Lk);
                lLev = Lk - 1; lIdx = Ls;
            } else if (Lph == 1) {
                Lrs = Ls + (1 << (Lk - 1));
                lLev = Lk - 2; lIdx = Lrs;
            }
            if (Rph == 0) {
                int len = N - Rp;
                Rk = (len >= (1 << LVLS)) ? LVLS : (31 - __clz(len));
                rLev = Rk - 1; rIdx = Rp;
            } else if (Rph == 1) {
                rLev = Rk - 2; rIdx = Rp;
            }
            float lx = 0.0f, lnv = 0.0f, rx = 0.0f, rnv = 0.0f;
            if (Lph != 2) {
                const float* bX = (lLev < 0) ? xs : (TX0 + lLev * N);
                const float* bN = (lLev < 0) ? xs : (TN0 + lLev * N);
                lx = bX[lIdx]; lnv = bN[lIdx];
            }
            if (Rph != 2) {
                const float* bX = (rLev < 0) ? xs : (TX0 + rLev * N);
                const float* bN = (rLev < 0) ? xs : (TN0 + rLev * N);
                rx = bX[rIdx]; rnv = bN[rIdx];
            }
            if (Lph == 0) {
                if (lx > v) Lph = (Lk == 0) ? 2 : 1;
                else { Lm = fminf(Lm, lnv); Lp = Ls - 1; if (Lp < 0) Lph = 2; }
            } else if (Lph == 1) {
                if (lx > v) Ls = Lrs; else Lm = fminf(Lm, lnv);
                if (--Lk == 0) Lph = 2;
            }
            if (Rph == 0) {
                if (rx > v) Rph = (Rk == 0) ? 2 : 1;
                else { Rm = fminf(Rm, rnv); Rp += (1 << Rk); if (Rp >= N) Rph = 2; }
            } else if (Rph == 1) {
                if (!(rx > v)) { Rm = fminf(Rm, rnv); Rp += (1 << (Rk - 1)); }
                if (--Rk == 0) Rph = 2;
            }
        }
        if (v - fmaxf(Lm, Rm) >= PROMF) keepres[i] = 1;
    }
    __syncthreads();

    float res[EL];
    #pragma unroll
    for (int e = 0; e < EL; ++e) res[e] = keepres[base + e] ? 1.0f : 0.0f;
    float* outr = out + row * (size_t)N + base;
    ((float4*)outr)[0] = make_float4(res[0], res[1], res[2], res[3]);
    ((float4*)outr)[1] = make_float4(res[4], res[5], res[6], res[7]);
}

extern "C" void kernel_launch(void* const* d_in, const int* in_sizes, int n_in,
                              void* d_out, int out_size, void* d_ws, size_t ws_size,
                              hipStream_t stream) {
    const float* x = (const float*)d_in[0];
    float* outp = (float*)d_out;
    const int rows = in_sizes[0] / N;
    // measurement probes (results discarded; amplify so each outranks ~39us fills)
    probe_kernel<1><<<rows, NT, 0, stream>>>(x, outp, 20);
    probe_kernel<2><<<rows, NT, 0, stream>>>(x, outp, 6);
    probe_kernel<3><<<rows, NT, 0, stream>>>(x, outp, 6);
    probe_kernel<4><<<rows, NT, 0, stream>>>(x, outp, 5);
    // real kernel: writes the full output last
    peak_kernel<<<rows, NT, 0, stream>>>(x, outp);
}

// Round 11
// 251.450 us; speedup vs baseline: 1.0018x; 1.0018x over previous
//
#include <hip/hip_runtime.h>

#define N 2048
#define NT 256
#define EL 8            // elements per thread
#define HEIGHTF 0.1f
#define PROMF 0.05f
#define LVLS 8          // sparse-table levels: windows 2,4,...,256

// ===================== measurement probe body =====================
// DEPTH=1: load+normalize+candidates+gather; 2:+suppression; 3:+tables; 4:+prominence
template<int DEPTH>
__device__ __forceinline__ void probe_body(const float* __restrict__ x, int reps) {
    __shared__ float xs[N];
    __shared__ float actl[16 + N + 24];
    __shared__ unsigned int nk32[3 + NT + 3];
    __shared__ float TMX[LVLS][N];
    __shared__ float TMN[LVLS][N];
    __shared__ float wred[8];
    __shared__ int wtot[4];
    __shared__ unsigned short klist[NT];
    __shared__ unsigned char keepres[N];
    __shared__ int donecnt;

    const int row = blockIdx.x;
    const int t = threadIdx.x;
    const int base = t * EL;
    const float* xr = x + row * (size_t)N;
    const int wv = t >> 6, ln = t & 63;

    for (int rep = 0; rep < reps; ++rep) {
        int z = 0;
        asm volatile("" : "+v"(z));   // opaque per-rep zero: defeats LICM
        __syncthreads();              // close previous rep

        // ---- phase 1 ----
        float4 Ld0 = ((const float4*)(xr + base + z))[0];
        float4 Ld1 = ((const float4*)(xr + base + z))[1];
        float v0[EL] = {Ld0.x, Ld0.y, Ld0.z, Ld0.w, Ld1.x, Ld1.y, Ld1.z, Ld1.w};
        float mn = v0[0], mx = v0[0];
        #pragma unroll
        for (int e = 1; e < EL; ++e) { mn = fminf(mn, v0[e]); mx = fmaxf(mx, v0[e]); }
        #pragma unroll
        for (int off = 32; off > 0; off >>= 1) {
            mn = fminf(mn, __shfl_xor(mn, off, 64));
            mx = fmaxf(mx, __shfl_xor(mx, off, 64));
        }
        if (ln == 0) { wred[wv] = mn; wred[4 + wv] = mx; }
        if (t < 16) actl[t] = -1e30f;
        if (t < 24) actl[16 + N + t] = -1e30f;
        __syncthreads();
        const float xmin = fminf(fminf(wred[0], wred[1]), fminf(wred[2], wred[3]));
        const float xmax = fmaxf(fmaxf(wred[4], wred[5]), fmaxf(wred[6], wred[7]));
        const float den = (xmax - xmin) + 1e-5f;
        float vn[EL];
        #pragma unroll
        for (int e = 0; e < EL; ++e) {
            vn[e] = (v0[e] - xmin) / den;
            xs[base + e] = vn[e];
        }
        __syncthreads();
        unsigned int undec = 0, kept = 0;
        #pragma unroll
        for (int e = 0; e < EL; ++e) {
            int i = base + e;
            float v = vn[e];
            float lf = (e == 0) ? ((i >= 1) ? xs[i-1] : 3e38f) : vn[e-1];
            float rt = (e == EL-1) ? ((i+1 < N) ? xs[i+1] : 3e38f) : vn[e+1];
            bool c = (i >= 1) && (i <= N-2) && (v > lf) && (v > rt) && (v >= HEIGHTF);
            if (c) undec |= (1u << e);
            actl[16 + i] = c ? v : -1e30f;
        }
        __syncthreads();
        float a[40];
        {
            const float4* ap = (const float4*)(actl + base);
            #pragma unroll
            for (int q = 0; q < 10; ++q) {
                float4 w = ap[q];
                a[4*q+0] = w.x; a[4*q+1] = w.y; a[4*q+2] = w.z; a[4*q+3] = w.w;
            }
        }
        asm volatile("" :: "v"(undec), "v"(a[16]), "v"(a[0]), "v"(a[39]));

        auto compute_wins = [&](unsigned int ud) -> unsigned int {
            float m2v[25], m4v[23], m8v[19];
            #pragma unroll
            for (int s = 0; s < 25; ++s) m2v[s] = fmaxf(a[7+s], a[8+s]);
            #pragma unroll
            for (int s = 0; s < 23; ++s) m4v[s] = fmaxf(m2v[s], m2v[s+2]);
            #pragma unroll
            for (int s = 0; s < 19; ++s) m8v[s] = fmaxf(m4v[s], m4v[s+4]);
            unsigned int wb = 0;
            #pragma unroll
            for (int e = 0; e < EL; ++e) {
                if (ud & (1u << e)) {
                    float v = a[16+e];
                    float wl = fmaxf(m8v[e], a[15+e]);
                    float wr = fmaxf(m8v[10+e], a[25+e]);
                    if (wl < v && wr <= v) wb |= (1u << e);
                }
            }
            return wb;
        };

        if constexpr (DEPTH >= 2) {
            nk32[t] = 0;
            if (t < 6) nk32[NT + t] = 0;
            if (t == 0) donecnt = 0;
            __syncthreads();
            volatile unsigned int* nkv = nk32 + 3;
            volatile int* dcp = (volatile int*)&donecnt;
            unsigned long long lastV = ~0ULL;
            bool counted = false;
            int guard = 0;
            while (true) {
                if (undec) {
                    unsigned long long V = 0;
                    #pragma unroll
                    for (int q = 0; q < 7; ++q)
                        V |= ((unsigned long long)(nkv[t - 3 + q] & 0xFFu)) << (8 * q);
                    V <<= 1;
                    if (V != lastV) {
                        lastV = V;
                        #pragma unroll
                        for (int s = 0; s < 40; ++s)
                            if ((V >> s) & 0x7FFFFULL) a[s] = -1e30f;
                        #pragma unroll
                        for (int e = 0; e < EL; ++e)
                            if (undec & (1u << e))
                                if ((V >> (16 + e)) & 0x7FFFFULL) undec &= ~(1u << e);
                        if (undec) {
                            unsigned int wb = compute_wins(undec);
                            if (wb) {
                                kept |= wb;
                                undec = 0;
                                nkv[t] = kept;
                            }
                        }
                    } else {
                        __builtin_amdgcn_s_sleep(1);
                    }
                }
                if (!undec && !counted) {
                    nkv[t] = kept;
                    __threadfence_block();
                    atomicAdd(&donecnt, 1);
                    counted = true;
                }
                if (*dcp >= NT) break;
                if (counted) __builtin_amdgcn_s_sleep(2);
                if (++guard > 65536) break;
            }
            __syncthreads();
            asm volatile("" :: "v"(kept));
        }

        int ktot = 0;
        if constexpr (DEPTH >= 3) {
            float cx[EL], cn[EL];
            #pragma unroll
            for (int j = 0; j < EL; ++j) {
                int i = t + j * NT;
                float a0 = xs[i];
                bool inb = (i + 1 < N);
                float nb = inb ? xs[i + 1] : 0.0f;
                cx[j] = fmaxf(a0, inb ? nb : -3e38f);
                cn[j] = fminf(a0, inb ? nb : 3e38f);
                TMX[0][i] = cx[j];
                TMN[0][i] = cn[j];
            }
            int myc = __popc(kept);
            int pre = myc;
            #pragma unroll
            for (int off = 1; off < 64; off <<= 1) {
                int up = __shfl_up(pre, off, 64);
                if (ln >= off) pre += up;
            }
            if (ln == 63) wtot[wv] = pre;
            #pragma unroll
            for (int e = 0; e < EL; ++e) keepres[base + e] = 0;
            __syncthreads();
            {
                int woff = 0;
                #pragma unroll
                for (int w = 0; w < 4; ++w) woff += (w < wv) ? wtot[w] : 0;
                int slot = woff + pre - myc;
                #pragma unroll
                for (int e = 0; e < EL; ++e)
                    if (kept & (1u << e)) klist[slot++] = (unsigned short)(base + e);
            }
            ktot = wtot[0] + wtot[1] + wtot[2] + wtot[3];
            #pragma unroll
            for (int pp = 0; pp < 3; ++pp) {
                const int Lv = 1 + 2 * pp;
                const int h = 1 << Lv;
                #pragma unroll
                for (int j = 0; j < EL; ++j) {
                    int i = t + j * NT;
                    float x1 = (i +   h < N) ? TMX[Lv-1][i+  h] : -3e38f;
                    float x2 = (i + 2*h < N) ? TMX[Lv-1][i+2*h] : -3e38f;
                    float x3 = (i + 3*h < N) ? TMX[Lv-1][i+3*h] : -3e38f;
                    float n1 = (i +   h < N) ? TMN[Lv-1][i+  h] : 3e38f;
                    float n2 = (i + 2*h < N) ? TMN[Lv-1][i+2*h] : 3e38f;
                    float n3 = (i + 3*h < N) ? TMN[Lv-1][i+3*h] : 3e38f;
                    float tx = fmaxf(cx[j], x1), tn = fminf(cn[j], n1);
                    TMX[Lv][i] = tx;  TMN[Lv][i] = tn;
                    cx[j] = fmaxf(tx, fmaxf(x2, x3));
                    cn[j] = fminf(tn, fminf(n2, n3));
                    TMX[Lv+1][i] = cx[j];  TMN[Lv+1][i] = cn[j];
                }
                __syncthreads();
            }
            {
                const int h = 128;
                #pragma unroll
                for (int j = 0; j < EL; ++j) {
                    int i = t + j * NT;
                    float x1 = (i + h < N) ? TMX[6][i+h] : -3e38f;
                    float n1 = (i + h < N) ? TMN[6][i+h] : 3e38f;
                    cx[j] = fmaxf(cx[j], x1);
                    cn[j] = fminf(cn[j], n1);
                    TMX[7][i] = cx[j];  TMN[7][i] = cn[j];
                }
                __syncthreads();
            }
            float live3 = TMX[7][t] + TMN[7][t + NT] + (float)ktot;
            asm volatile("" :: "v"(live3));
        }

        if constexpr (DEPTH >= 4) {
            if (t < ktot) {
                const int i = klist[t];
                const float v = xs[i];
                const float* TX0 = &TMX[0][0];
                const float* TN0 = &TMN[0][0];
                int Lph = 0, Lp = i - 1, Lk = 0, Ls = 0;
                float Lm = v;
                if (Lp < 0) Lph = 2;
                int Rph = 0, Rp = i + 1, Rk = 0;
                float Rm = v;
                if (Rp >= N) Rph = 2;
                while (Lph != 2 || Rph != 2) {
                    int lLev = 0, lIdx = 0, rLev = 0, rIdx = 0, Lrs = 0;
                    if (Lph == 0) {
                        int len = Lp + 1;
                        Lk = (len >= (1 << LVLS)) ? LVLS : (31 - __clz(len));
                        Ls = Lp + 1 - (1 << Lk);
                        lLev = Lk - 1; lIdx = Ls;
                    } else if (Lph == 1) {
                        Lrs = Ls + (1 << (Lk - 1));
                        lLev = Lk - 2; lIdx = Lrs;
                    }
                    if (Rph == 0) {
                        int len = N - Rp;
                        Rk = (len >= (1 << LVLS)) ? LVLS : (31 - __clz(len));
                        rLev = Rk - 1; rIdx = Rp;
                    } else if (Rph == 1) {
                        rLev = Rk - 2; rIdx = Rp;
                    }
                    float lx = 0.0f, lnv = 0.0f, rx = 0.0f, rnv = 0.0f;
                    if (Lph != 2) {
                        const float* bX = (lLev < 0) ? xs : (TX0 + lLev * N);
                        const float* bN = (lLev < 0) ? xs : (TN0 + lLev * N);
                        lx = bX[lIdx]; lnv = bN[lIdx];
                    }
                    if (Rph != 2) {
                        const float* bX = (rLev < 0) ? xs : (TX0 + rLev * N);
                        const float* bN = (rLev < 0) ? xs : (TN0 + rLev * N);
                        rx = bX[rIdx]; rnv = bN[rIdx];
                    }
                    if (Lph == 0) {
                        if (lx > v) Lph = (Lk == 0) ? 2 : 1;
                        else { Lm = fminf(Lm, lnv); Lp = Ls - 1; if (Lp < 0) Lph = 2; }
                    } else if (Lph == 1) {
                        if (lx > v) Ls = Lrs; else Lm = fminf(Lm, lnv);
                        if (--Lk == 0) Lph = 2;
                    }
                    if (Rph == 0) {
                        if (rx > v) Rph = (Rk == 0) ? 2 : 1;
                        else { Rm = fminf(Rm, rnv); Rp += (1 << Rk); if (Rp >= N) Rph = 2; }
                    } else if (Rph == 1) {
                        if (!(rx > v)) { Rm = fminf(Rm, rnv); Rp += (1 << (Rk - 1)); }
                        if (--Rk == 0) Rph = 2;
                    }
                }
                if (v - fmaxf(Lm, Rm) >= PROMF) keepres[i] = 1;
            }
            __syncthreads();
            float live4 = (float)keepres[base] + (float)keepres[base + 7];
            asm volatile("" :: "v"(live4));
        }
    }
}

// distinctly-NAMED probe wrappers so rocprof rows are attributable
__global__ __launch_bounds__(NT) void probe_d1(const float* __restrict__ x, int reps) { probe_body<1>(x, reps); }
__global__ __launch_bounds__(NT) void probe_d2(const float* __restrict__ x, int reps) { probe_body<2>(x, reps); }
__global__ __launch_bounds__(NT) void probe_d3(const float* __restrict__ x, int reps) { probe_body<3>(x, reps); }
__global__ __launch_bounds__(NT) void probe_d4(const float* __restrict__ x, int reps) { probe_body<4>(x, reps); }

// ===================== real kernel (R9, verified) =====================
__global__ __launch_bounds__(NT)
void peak_kernel(const float* __restrict__ x, float* __restrict__ out) {
    __shared__ float xs[N];
    __shared__ float actl[16 + N + 24];
    __shared__ unsigned int nk32[3 + NT + 3];
    __shared__ float TMX[LVLS][N];
    __shared__ float TMN[LVLS][N];
    __shared__ float wred[8];
    __shared__ int wtot[4];
    __shared__ unsigned short klist[NT];
    __shared__ unsigned char keepres[N];
    __shared__ int donecnt;

    const int row = blockIdx.x;
    const int t = threadIdx.x;
    const int base = t * EL;
    const float* xr = x + row * (size_t)N;
    const int wv = t >> 6, ln = t & 63;

    float4 Ld0 = ((const float4*)(xr + base))[0];
    float4 Ld1 = ((const float4*)(xr + base))[1];
    float v0[EL] = {Ld0.x, Ld0.y, Ld0.z, Ld0.w, Ld1.x, Ld1.y, Ld1.z, Ld1.w};
    float mn = v0[0], mx = v0[0];
    #pragma unroll
    for (int e = 1; e < EL; ++e) { mn = fminf(mn, v0[e]); mx = fmaxf(mx, v0[e]); }
    #pragma unroll
    for (int off = 32; off > 0; off >>= 1) {
        mn = fminf(mn, __shfl_xor(mn, off, 64));
        mx = fmaxf(mx, __shfl_xor(mx, off, 64));
    }
    if (ln == 0) { wred[wv] = mn; wred[4 + wv] = mx; }
    nk32[t] = 0;
    if (t < 6) nk32[NT + t] = 0;
    if (t == 0) donecnt = 0;
    if (t < 16) actl[t] = -1e30f;
    if (t < 24) actl[16 + N + t] = -1e30f;
    __syncthreads();

    const float xmin = fminf(fminf(wred[0], wred[1]), fminf(wred[2], wred[3]));
    const float xmax = fmaxf(fmaxf(wred[4], wred[5]), fmaxf(wred[6], wred[7]));
    const float den = (xmax - xmin) + 1e-5f;
    float vn[EL];
    #pragma unroll
    for (int e = 0; e < EL; ++e) {
        vn[e] = (v0[e] - xmin) / den;
        xs[base + e] = vn[e];
    }
    __syncthreads();

    unsigned int undec = 0, kept = 0;
    #pragma unroll
    for (int e = 0; e < EL; ++e) {
        int i = base + e;
        float v = vn[e];
        float lf = (e == 0) ? ((i >= 1) ? xs[i-1] : 3e38f) : vn[e-1];
        float rt = (e == EL-1) ? ((i+1 < N) ? xs[i+1] : 3e38f) : vn[e+1];
        bool c = (i >= 1) && (i <= N-2) && (v > lf) && (v > rt) && (v >= HEIGHTF);
        if (c) undec |= (1u << e);
        actl[16 + i] = c ? v : -1e30f;
    }
    __syncthreads();

    float a[40];
    {
        const float4* ap = (const float4*)(actl + base);
        #pragma unroll
        for (int q = 0; q < 10; ++q) {
            float4 w = ap[q];
            a[4*q+0] = w.x; a[4*q+1] = w.y; a[4*q+2] = w.z; a[4*q+3] = w.w;
        }
    }

    auto compute_wins = [&](unsigned int ud) -> unsigned int {
        float m2v[25], m4v[23], m8v[19];
        #pragma unroll
        for (int s = 0; s < 25; ++s) m2v[s] = fmaxf(a[7+s], a[8+s]);
        #pragma unroll
        for (int s = 0; s < 23; ++s) m4v[s] = fmaxf(m2v[s], m2v[s+2]);
        #pragma unroll
        for (int s = 0; s < 19; ++s) m8v[s] = fmaxf(m4v[s], m4v[s+4]);
        unsigned int wb = 0;
        #pragma unroll
        for (int e = 0; e < EL; ++e) {
            if (ud & (1u << e)) {
                float v = a[16+e];
                float wl = fmaxf(m8v[e], a[15+e]);
                float wr = fmaxf(m8v[10+e], a[25+e]);
                if (wl < v && wr <= v) wb |= (1u << e);
            }
        }
        return wb;
    };

    {
        volatile unsigned int* nkv = nk32 + 3;
        volatile int* dcp = (volatile int*)&donecnt;
        unsigned long long lastV = ~0ULL;
        bool counted = false;
        int guard = 0;
        while (true) {
            if (undec) {
                unsigned long long V = 0;
                #pragma unroll
                for (int q = 0; q < 7; ++q)
                    V |= ((unsigned long long)(nkv[t - 3 + q] & 0xFFu)) << (8 * q);
                V <<= 1;
                if (V != lastV) {
                    lastV = V;
                    #pragma unroll
                    for (int s = 0; s < 40; ++s)
                        if ((V >> s) & 0x7FFFFULL) a[s] = -1e30f;
                    #pragma unroll
                    for (int e = 0; e < EL; ++e)
                        if (undec & (1u << e))
                            if ((V >> (16 + e)) & 0x7FFFFULL) undec &= ~(1u << e);
                    if (undec) {
                        unsigned int wb = compute_wins(undec);
                        if (wb) {
                            kept |= wb;
                            undec = 0;
                            nkv[t] = kept;
                        }
                    }
                } else {
                    __builtin_amdgcn_s_sleep(1);
                }
            }
            if (!undec && !counted) {
                nkv[t] = kept;
                __threadfence_block();
                atomicAdd(&donecnt, 1);
                counted = true;
            }
            if (*dcp >= NT) break;
            if (counted) __builtin_amdgcn_s_sleep(2);
            if (++guard > 65536) break;
        }
    }
    __syncthreads();

    float cx[EL], cn[EL];
    #pragma unroll
    for (int j = 0; j < EL; ++j) {
        int i = t + j * NT;
        float a0 = xs[i];
        bool inb = (i + 1 < N);
        float nb = inb ? xs[i + 1] : 0.0f;
        cx[j] = fmaxf(a0, inb ? nb : -3e38f);
        cn[j] = fminf(a0, inb ? nb : 3e38f);
        TMX[0][i] = cx[j];
        TMN[0][i] = cn[j];
    }
    int myc = __popc(kept);
    int pre = myc;
    #pragma unroll
    for (int off = 1; off < 64; off <<= 1) {
        int up = __shfl_up(pre, off, 64);
        if (ln >= off) pre += up;
    }
    if (ln == 63) wtot[wv] = pre;
    #pragma unroll
    for (int e = 0; e < EL; ++e) keepres[base + e] = 0;
    __syncthreads();

    {
        int woff = 0;
        #pragma unroll
        for (int w = 0; w < 4; ++w) woff += (w < wv) ? wtot[w] : 0;
        int slot = woff + pre - myc;
        #pragma unroll
        for (int e = 0; e < EL; ++e)
            if (kept & (1u << e)) klist[slot++] = (unsigned short)(base + e);
    }
    const int ktot = wtot[0] + wtot[1] + wtot[2] + wtot[3];
    #pragma unroll
    for (int pp = 0; pp < 3; ++pp) {
        const int Lv = 1 + 2 * pp;
        const int h = 1 << Lv;
        #pragma unroll
        for (int j = 0; j < EL; ++j) {
            int i = t + j * NT;
            float x1 = (i +   h < N) ? TMX[Lv-1][i+  h] : -3e38f;
            float x2 = (i + 2*h < N) ? TMX[Lv-1][i+2*h] : -3e38f;
            float x3 = (i + 3*h < N) ? TMX[Lv-1][i+3*h] : -3e38f;
            float n1 = (i +   h < N) ? TMN[Lv-1][i+  h] : 3e38f;
            float n2 = (i + 2*h < N) ? TMN[Lv-1][i+2*h] : 3e38f;
            float n3 = (i + 3*h < N) ? TMN[Lv-1][i+3*h] : 3e38f;
            float tx = fmaxf(cx[j], x1), tn = fminf(cn[j], n1);
            TMX[Lv][i] = tx;  TMN[Lv][i] = tn;
            cx[j] = fmaxf(tx, fmaxf(x2, x3));
            cn[j] = fminf(tn, fminf(n2, n3));
            TMX[Lv+1][i] = cx[j];  TMN[Lv+1][i] = cn[j];
        }
        __syncthreads();
    }
    {
        const int h = 128;
        #pragma unroll
        for (int j = 0; j < EL; ++j) {
            int i = t + j * NT;
            float x1 = (i + h < N) ? TMX[6][i+h] : -3e38f;
            float n1 = (i + h < N) ? TMN[6][i+h] : 3e38f;
            cx[j] = fmaxf(cx[j], x1);
            cn[j] = fminf(cn[j], n1);
            TMX[7][i] = cx[j];  TMN[7][i] = cn[j];
        }
        __syncthreads();
    }

    if (t < ktot) {
        const int i = klist[t];
        const float v = xs[i];
        const float* TX0 = &TMX[0][0];
        const float* TN0 = &TMN[0][0];
        int Lph = 0, Lp = i - 1, Lk = 0, Ls = 0;
        float Lm = v;
        if (Lp < 0) Lph = 2;
        int Rph = 0, Rp = i + 1, Rk = 0;
        float Rm = v;
        if (Rp >= N) Rph = 2;
        while (Lph != 2 || Rph != 2) {
            int lLev = 0, lIdx = 0, rLev = 0, rIdx = 0, Lrs = 0;
            if (Lph == 0) {
                int len = Lp + 1;
                Lk = (len >= (1 << LVLS)) ? LVLS : (31 - __clz(len));
                Ls = Lp + 1 - (1 << Lk);
                lLev = Lk - 1; lIdx = Ls;
            } else if (Lph == 1) {
                Lrs = Ls + (1 << (Lk - 1));
                lLev = Lk - 2; lIdx = Lrs;
            }
            if (Rph == 0) {
                int len = N - Rp;
                Rk = (len >= (1 << LVLS)) ? LVLS : (31 - __clz(len));
                rLev = Rk - 1; rIdx = Rp;
            } else if (Rph == 1) {
                rLev = Rk - 2; rIdx = Rp;
            }
            float lx = 0.0f, lnv = 0.0f, rx = 0.0f, rnv = 0.0f;
            if (Lph != 2) {
                const float* bX = (lLev < 0) ? xs : (TX0 + lLev * N);
                const float* bN = (lLev < 0) ? xs : (TN0 + lLev * N);
                lx = bX[lIdx]; lnv = bN[lIdx];
            }
            if (Rph != 2) {
                const float* bX = (rLev < 0) ? xs : (TX0 + rLev * N);
                const float* bN = (rLev < 0) ? xs : (TN0 + rLev * N);
                rx = bX[rIdx]; rnv = bN[rIdx];
            }
            if (Lph == 0) {
                if (lx > v) Lph = (Lk == 0) ? 2 : 1;
                else { Lm = fminf(Lm, lnv); Lp = Ls - 1; if (Lp < 0) Lph = 2; }
            } else if (Lph == 1) {
                if (lx > v) Ls = Lrs; else Lm = fminf(Lm, lnv);
                if (--Lk == 0) Lph = 2;
            }
            if (Rph == 0) {
                if (rx > v) Rph = (Rk == 0) ? 2 : 1;
                else { Rm = fminf(Rm, rnv); Rp += (1 << Rk); if (Rp >= N) Rph = 2; }
            } else if (Rph == 1) {
                if (!(rx > v)) { Rm = fminf(Rm, rnv); Rp += (1 << (Rk - 1)); }
                if (--Rk == 0) Rph = 2;
            }
        }
        if (v - fmaxf(Lm, Rm) >= PROMF) keepres[i] = 1;
    }
    __syncthreads();

    float res[EL];
    #pragma unroll
    for (int e = 0; e < EL; ++e) res[e] = keepres[base + e] ? 1.0f : 0.0f;
    float* outr = out + row * (size_t)N + base;
    ((float4*)outr)[0] = make_float4(res[0], res[1], res[2], res[3]);
    ((float4*)outr)[1] = make_float4(res[4], res[5], res[6], res[7]);
}

extern "C" void kernel_launch(void* const* d_in, const int* in_sizes, int n_in,
                              void* d_out, int out_size, void* d_ws, size_t ws_size,
                              hipStream_t stream) {
    const float* x = (const float*)d_in[0];
    float* outp = (float*)d_out;
    const int rows = in_sizes[0] / N;
    // measurement probes (distinct names; reps keep each above the ~39us fills)
    probe_d1<<<rows, NT, 0, stream>>>(x, 30);
    probe_d2<<<rows, NT, 0, stream>>>(x, 7);
    probe_d3<<<rows, NT, 0, stream>>>(x, 6);
    probe_d4<<<rows, NT, 0, stream>>>(x, 5);
    // real kernel: writes the full output last
    peak_kernel<<<rows, NT, 0, stream>>>(x, outp);
}

// Round 12
// 75.797 us; speedup vs baseline: 3.3233x; 3.3174x over previous
//
#include <hip/hip_runtime.h>

#define N 2048
#define NT 256
#define EL 8            // elements per thread
#define HEIGHTF 0.1f
#define PROMF 0.05f
#define LVLS 8          // sparse-table levels: windows 2,4,...,256

__global__ __launch_bounds__(NT)
void peak_kernel(const float* __restrict__ x, float* __restrict__ out) {
    __shared__ float xs[N];
    __shared__ float actl[24 + N + 32];       // act with -inf guards (pos p -> actl[24+p])
    __shared__ unsigned int nk32[3 + NT + 3]; // CUMULATIVE kept masks, 3 guard words/side
    __shared__ float TMX[LVLS][N];
    __shared__ float TMN[LVLS][N];
    __shared__ float wred[8];
    __shared__ int wtot[4];
    __shared__ unsigned short klist[NT];
    __shared__ unsigned char keepres[N];
    __shared__ int donecnt;

    const int row = blockIdx.x;
    const int t = threadIdx.x;
    const int base = t * EL;
    const float* xr = x + row * (size_t)N;
    const int wv = t >> 6, ln = t & 63;

    // ---- 1. load + exact min/max + init ----
    float4 Ld0 = ((const float4*)(xr + base))[0];
    float4 Ld1 = ((const float4*)(xr + base))[1];
    float v0[EL] = {Ld0.x, Ld0.y, Ld0.z, Ld0.w, Ld1.x, Ld1.y, Ld1.z, Ld1.w};
    float mn = v0[0], mx = v0[0];
    #pragma unroll
    for (int e = 1; e < EL; ++e) { mn = fminf(mn, v0[e]); mx = fmaxf(mx, v0[e]); }
    #pragma unroll
    for (int off = 32; off > 0; off >>= 1) {
        mn = fminf(mn, __shfl_xor(mn, off, 64));
        mx = fmaxf(mx, __shfl_xor(mx, off, 64));
    }
    if (ln == 0) { wred[wv] = mn; wred[4 + wv] = mx; }
    nk32[t] = 0;
    if (t < 6) nk32[NT + t] = 0;
    if (t == 0) donecnt = 0;
    if (t < 24) actl[t] = -1e30f;              // positions -24..-1
    if (t < 32) actl[24 + N + t] = -1e30f;     // positions N..N+31
    __syncthreads();

    // ---- 2. normalize (exact IEEE f32 division, matches reference) ----
    const float xmin = fminf(fminf(wred[0], wred[1]), fminf(wred[2], wred[3]));
    const float xmax = fmaxf(fmaxf(wred[4], wred[5]), fmaxf(wred[6], wred[7]));
    const float den = (xmax - xmin) + 1e-5f;
    float vn[EL];
    #pragma unroll
    for (int e = 0; e < EL; ++e) {
        vn[e] = (v0[e] - xmin) / den;
        xs[base + e] = vn[e];
    }
    __syncthreads();

    // ---- 3. candidates (strict local max & height) ----
    unsigned int undec = 0, kept = 0;
    #pragma unroll
    for (int e = 0; e < EL; ++e) {
        int i = base + e;
        float v = vn[e];
        float lf = (e == 0) ? ((i >= 1) ? xs[i-1] : 3e38f) : vn[e-1];
        float rt = (e == EL-1) ? ((i+1 < N) ? xs[i+1] : 3e38f) : vn[e+1];
        bool c = (i >= 1) && (i <= N-2) && (v > lf) && (v > rt) && (v >= HEIGHTF);
        if (c) undec |= (1u << e);
        actl[24 + i] = c ? v : -1e30f;
    }
    __syncthreads();

    // ---- 4. register act window a[56] = positions [base-24, base+32) ----
    float a[56];
    {
        const float4* ap = (const float4*)(actl + base);  // actl[base] = pos base-24
        #pragma unroll
        for (int q = 0; q < 14; ++q) {
            float4 w = ap[q];
            a[4*q+0] = w.x; a[4*q+1] = w.y; a[4*q+2] = w.z; a[4*q+3] = w.w;
        }
    }

    volatile unsigned int* nkv = nk32 + 3;

    // W bit s (s in [9,47)) = derived winner at window position s.
    // (positions with full +-9 context inside the window; tie rules:
    //  left tie beats -> strict <, right tie loses -> <=)
    auto compute_W = [&]() -> unsigned long long {
        unsigned long long W = 0;
        {   // half 1: s in [9,28), context a[0..38)
            float m2[37], m4[35];
            #pragma unroll
            for (int s2 = 0; s2 < 37; ++s2) m2[s2] = fmaxf(a[s2], a[s2+1]);
            #pragma unroll
            for (int s4 = 0; s4 < 35; ++s4) m4[s4] = fmaxf(m2[s4], m2[s4+2]);
            #pragma unroll
            for (int s = 9; s < 28; ++s) {
                float v = a[s];
                float wl = fmaxf(fmaxf(m4[s-9], m4[s-5]), a[s-1]);  // max a[s-9..s-1]
                float wr = fmaxf(fmaxf(m4[s+1], m4[s+5]), a[s+9]);  // max a[s+1..s+9]
                if (wl < v && wr <= v) W |= (1ULL << s);
            }
        }
        {   // half 2: s in [28,47), context a[19..56)
            float m2[36], m4[34];
            #pragma unroll
            for (int s2 = 0; s2 < 36; ++s2) m2[s2] = fmaxf(a[19+s2], a[20+s2]);
            #pragma unroll
            for (int s4 = 0; s4 < 34; ++s4) m4[s4] = fmaxf(m2[s4], m2[s4+2]);
            #pragma unroll
            for (int s = 28; s < 47; ++s) {
                float v = a[s];
                float wl = fmaxf(fmaxf(m4[s-28], m4[s-24]), a[s-1]);
                float wr = fmaxf(fmaxf(m4[s-18], m4[s-14]), a[s+9]);
                if (wl < v && wr <= v) W |= (1ULL << s);
            }
        }
        return W;
    };

    // apply a winner-mask (bit s = winner at window pos s): clear act within
    // +-9 of winners, decide own elems, publish cumulative kept on change.
    auto apply_mask = [&](unsigned long long Wm) {
        #pragma unroll
        for (int s = 0; s < 56; ++s) {
            unsigned long long m = (s >= 9) ? ((Wm >> (s-9)) & 0x7FFFFULL)
                                            : (Wm & ((1ULL << (s+10)) - 1));
            if (m) a[s] = -1e30f;
        }
        unsigned int oldk = kept;
        #pragma unroll
        for (int e = 0; e < EL; ++e) {
            if (undec & (1u << e)) {
                const int s = 24 + e;
                unsigned long long w19 = (Wm >> (s-9)) & 0x7FFFFULL;
                if ((w19 >> 9) & 1ULL) { kept |= (1u << e); undec &= ~(1u << e); }
                else if (w19)          { undec &= ~(1u << e); }
            }
        }
        if (kept != oldk) nkv[t] = kept;
    };

    auto resolve = [&]() {   // local fixpoint over the window
        while (true) {
            unsigned long long W = compute_W();
            if (!W) break;
            apply_mask(W);
        }
    };

    // ---- 5. ASYNC suppression (== scipy highest-first greedy) with
    //          widened-window local inference; no sleep on active path ----
    {
        volatile int* dcp = (volatile int*)&donecnt;
        unsigned long long lastV = 0;
        bool counted = false;
        int guard = 0;
        if (undec) resolve();   // initial local fixpoint (0 exchanges)
        while (true) {
            if (undec) {
                unsigned long long V = 0;   // V bit s = published winner at pos base-24+s
                #pragma unroll
                for (int q = 0; q < 7; ++q)
                    V |= ((unsigned long long)(nkv[t - 3 + q] & 0xFFu)) << (8 * q);
                if (V != lastV) {
                    lastV = V;
                    apply_mask(V);          // external facts: clears + own decisions
                    if (undec) resolve();   // re-derive with new knowledge
                }
            }
            if (!undec && !counted) {
                nkv[t] = kept;
                __threadfence_block();
                atomicAdd(&donecnt, 1);
                counted = true;
            }
            if (*dcp >= NT) break;
            if (counted) __builtin_amdgcn_s_sleep(2);
            if (++guard > 65536) break;
        }
    }
    __syncthreads();

    // ---- 6a. level-0 tables + kept prefix + clear map ----
    float cx[EL], cn[EL];
    #pragma unroll
    for (int j = 0; j < EL; ++j) {
        int i = t + j * NT;
        float a0 = xs[i];
        bool inb = (i + 1 < N);
        float nb = inb ? xs[i + 1] : 0.0f;
        cx[j] = fmaxf(a0, inb ? nb : -3e38f);
        cn[j] = fminf(a0, inb ? nb : 3e38f);
        TMX[0][i] = cx[j];
        TMN[0][i] = cn[j];
    }
    int myc = __popc(kept);
    int pre = myc;
    #pragma unroll
    for (int off = 1; off < 64; off <<= 1) {
        int up = __shfl_up(pre, off, 64);
        if (ln >= off) pre += up;
    }
    if (ln == 63) wtot[wv] = pre;
    #pragma unroll
    for (int e = 0; e < EL; ++e) keepres[base + e] = 0;
    __syncthreads();

    // ---- 6b. klist scatter + dual-level table build ----
    {
        int woff = 0;
        #pragma unroll
        for (int w = 0; w < 4; ++w) woff += (w < wv) ? wtot[w] : 0;
        int slot = woff + pre - myc;
        #pragma unroll
        for (int e = 0; e < EL; ++e)
            if (kept & (1u << e)) klist[slot++] = (unsigned short)(base + e);
    }
    const int ktot = wtot[0] + wtot[1] + wtot[2] + wtot[3];
    #pragma unroll
    for (int pp = 0; pp < 3; ++pp) {               // pairs (1,2) (3,4) (5,6)
        const int Lv = 1 + 2 * pp;
        const int h = 1 << Lv;
        #pragma unroll
        for (int j = 0; j < EL; ++j) {
            int i = t + j * NT;
            float x1 = (i +   h < N) ? TMX[Lv-1][i+  h] : -3e38f;
            float x2 = (i + 2*h < N) ? TMX[Lv-1][i+2*h] : -3e38f;
            float x3 = (i + 3*h < N) ? TMX[Lv-1][i+3*h] : -3e38f;
            float n1 = (i +   h < N) ? TMN[Lv-1][i+  h] : 3e38f;
            float n2 = (i + 2*h < N) ? TMN[Lv-1][i+2*h] : 3e38f;
            float n3 = (i + 3*h < N) ? TMN[Lv-1][i+3*h] : 3e38f;
            float tx = fmaxf(cx[j], x1), tn = fminf(cn[j], n1);
            TMX[Lv][i] = tx;  TMN[Lv][i] = tn;
            cx[j] = fmaxf(tx, fmaxf(x2, x3));
            cn[j] = fminf(tn, fminf(n2, n3));
            TMX[Lv+1][i] = cx[j];  TMN[Lv+1][i] = cn[j];
        }
        __syncthreads();
    }
    {                                               // level 7
        const int h = 128;
        #pragma unroll
        for (int j = 0; j < EL; ++j) {
            int i = t + j * NT;
            float x1 = (i + h < N) ? TMX[6][i+h] : -3e38f;
            float n1 = (i + h < N) ? TMN[6][i+h] : 3e38f;
            cx[j] = fmaxf(cx[j], x1);
            cn[j] = fminf(cn[j], n1);
            TMX[7][i] = cx[j];  TMN[7][i] = cn[j];
        }
        __syncthreads();
    }

    // ---- 7. prominence: one peak/thread, L+R walks interleaved ----
    if (t < ktot) {
        const int i = klist[t];
        const float v = xs[i];
        const float* TX0 = &TMX[0][0];
        const float* TN0 = &TMN[0][0];
        int Lph = 0, Lp = i - 1, Lk = 0, Ls = 0;
        float Lm = v;
        if (Lp < 0) Lph = 2;
        int Rph = 0, Rp = i + 1, Rk = 0;
        float Rm = v;
        if (Rp >= N) Rph = 2;
        while (Lph != 2 || Rph != 2) {
            int lLev = 0, lIdx = 0, rLev = 0, rIdx = 0, Lrs = 0;
            if (Lph == 0) {
                int len = Lp + 1;
                Lk = (len >= (1 << LVLS)) ? LVLS : (31 - __clz(len));
                Ls = Lp + 1 - (1 << Lk);
                lLev = Lk - 1; lIdx = Ls;
            } else if (Lph == 1) {
                Lrs = Ls + (1 << (Lk - 1));
                lLev = Lk - 2; lIdx = Lrs;
            }
            if (Rph == 0) {
                int len = N - Rp;
                Rk = (len >= (1 << LVLS)) ? LVLS : (31 - __clz(len));
                rLev = Rk - 1; rIdx = Rp;
            } else if (Rph == 1) {
                rLev = Rk - 2; rIdx = Rp;
            }
            float lx = 0.0f, lnv = 0.0f, rx = 0.0f, rnv = 0.0f;
            if (Lph != 2) {
                const float* bX = (lLev < 0) ? xs : (TX0 + lLev * N);
                const float* bN = (lLev < 0) ? xs : (TN0 + lLev * N);
                lx = bX[lIdx]; lnv = bN[lIdx];
            }
            if (Rph != 2) {
                const float* bX = (rLev < 0) ? xs : (TX0 + rLev * N);
                const float* bN = (rLev < 0) ? xs : (TN0 + rLev * N);
                rx = bX[rIdx]; rnv = bN[rIdx];
            }
            if (Lph == 0) {
                if (lx > v) Lph = (Lk == 0) ? 2 : 1;
                else { Lm = fminf(Lm, lnv); Lp = Ls - 1; if (Lp < 0) Lph = 2; }
            } else if (Lph == 1) {
                if (lx > v) Ls = Lrs; else Lm = fminf(Lm, lnv);
                if (--Lk == 0) Lph = 2;
            }
            if (Rph == 0) {
                if (rx > v) Rph = (Rk == 0) ? 2 : 1;
                else { Rm = fminf(Rm, rnv); Rp += (1 << Rk); if (Rp >= N) Rph = 2; }
            } else if (Rph == 1) {
                if (!(rx > v)) { Rm = fminf(Rm, rnv); Rp += (1 << (Rk - 1)); }
                if (--Rk == 0) Rph = 2;
            }
        }
        if (v - fmaxf(Lm, Rm) >= PROMF) keepres[i] = 1;
    }
    __syncthreads();

    // ---- 8. output ----
    float res[EL];
    #pragma unroll
    for (int e = 0; e < EL; ++e) res[e] = keepres[base + e] ? 1.0f : 0.0f;
    float* outr = out + row * (size_t)N + base;
    ((float4*)outr)[0] = make_float4(res[0], res[1], res[2], res[3]);
    ((float4*)outr)[1] = make_float4(res[4], res[5], res[6], res[7]);
}

extern "C" void kernel_launch(void* const* d_in, const int* in_sizes, int n_in,
                              void* d_out, int out_size, void* d_ws, size_t ws_size,
                              hipStream_t stream) {
    const float* x = (const float*)d_in[0];
    float* outp = (float*)d_out;
    const int rows = in_sizes[0] / N;
    peak_kernel<<<rows, NT, 0, stream>>>(x, outp);
}

// Round 13
// 23.699 us; speedup vs baseline: 10.6292x; 3.1984x over previous
//
#include <hip/hip_runtime.h>

#define N 2048
#define NT 256
#define EL 8            // elements per thread
#define HEIGHTF 0.1f
#define PROMF 0.05f
#define LVLS 8          // sparse-table levels: windows 2,4,...,256

__global__ __launch_bounds__(NT)
void peak_kernel(const float* __restrict__ x, float* __restrict__ out) {
    __shared__ float xs[N];
    __shared__ float actl[16 + N + 24];       // act with -inf guards (pos p -> actl[16+p])
    __shared__ unsigned int nk32[3 + NT + 3]; // CUMULATIVE kept masks, 3 guard words/side
    __shared__ float TMX[LVLS][N];            // TMX[k][i] = max xs[i, min(i+2^(k+1), N))
    __shared__ float TMN[LVLS][N];
    __shared__ float wred[8];
    __shared__ int wtot[4];
    __shared__ int wdone[4];
    __shared__ unsigned short klist[NT];
    __shared__ unsigned char keepres[N];

    const int row = blockIdx.x;
    const int t = threadIdx.x;
    const int base = t * EL;
    const float* xr = x + row * (size_t)N;
    const int wv = t >> 6, ln = t & 63;

    // ---- 1. load + exact min/max + init ----
    float4 Ld0 = ((const float4*)(xr + base))[0];
    float4 Ld1 = ((const float4*)(xr + base))[1];
    float v0[EL] = {Ld0.x, Ld0.y, Ld0.z, Ld0.w, Ld1.x, Ld1.y, Ld1.z, Ld1.w};
    float mn = v0[0], mx = v0[0];
    #pragma unroll
    for (int e = 1; e < EL; ++e) { mn = fminf(mn, v0[e]); mx = fmaxf(mx, v0[e]); }
    #pragma unroll
    for (int off = 32; off > 0; off >>= 1) {
        mn = fminf(mn, __shfl_xor(mn, off, 64));
        mx = fmaxf(mx, __shfl_xor(mx, off, 64));
    }
    if (ln == 0) { wred[wv] = mn; wred[4 + wv] = mx; }
    nk32[t] = 0;
    if (t < 6) nk32[NT + t] = 0;
    if (t < 4) wdone[t] = 0;
    if (t < 16) actl[t] = -1e30f;              // positions -16..-1
    if (t < 24) actl[16 + N + t] = -1e30f;     // positions N..N+23
    __syncthreads();

    // ---- 2. normalize (exact IEEE f32 division, matches reference) ----
    const float xmin = fminf(fminf(wred[0], wred[1]), fminf(wred[2], wred[3]));
    const float xmax = fmaxf(fmaxf(wred[4], wred[5]), fmaxf(wred[6], wred[7]));
    const float den = (xmax - xmin) + 1e-5f;
    float vn[EL];
    #pragma unroll
    for (int e = 0; e < EL; ++e) {
        vn[e] = (v0[e] - xmin) / den;
        xs[base + e] = vn[e];
    }
    __syncthreads();

    // ---- 3. candidates + level-0 tables + clear keepres ----
    unsigned int undec = 0, kept = 0;
    #pragma unroll
    for (int e = 0; e < EL; ++e) {
        int i = base + e;
        float v = vn[e];
        float lf = (e == 0) ? ((i >= 1) ? xs[i-1] : 3e38f) : vn[e-1];
        float rt = (e == EL-1) ? ((i+1 < N) ? xs[i+1] : 3e38f) : vn[e+1];
        bool c = (i >= 1) && (i <= N-2) && (v > lf) && (v > rt) && (v >= HEIGHTF);
        if (c) undec |= (1u << e);
        actl[16 + i] = c ? v : -1e30f;
        keepres[i] = 0;
    }
    float cx[EL], cn[EL];
    #pragma unroll
    for (int j = 0; j < EL; ++j) {            // level 0: stride-NT, conflict-free
        int i = t + j * NT;
        float a0 = xs[i];
        bool inb = (i + 1 < N);
        float nb = inb ? xs[i + 1] : 0.0f;
        cx[j] = fmaxf(a0, inb ? nb : -3e38f);
        cn[j] = fminf(a0, inb ? nb : 3e38f);
        TMX[0][i] = cx[j];
        TMN[0][i] = cn[j];
    }
    __syncthreads();

    // ---- 4. register act window a[40] = positions [base-16, base+24) ----
    float a[40];
    {
        const float4* ap = (const float4*)(actl + base);  // actl[base] = pos base-16
        #pragma unroll
        for (int q = 0; q < 10; ++q) {
            float4 w = ap[q];
            a[4*q+0] = w.x; a[4*q+1] = w.y; a[4*q+2] = w.z; a[4*q+3] = w.w;
        }
    }

    auto compute_wins = [&](unsigned int ud) -> unsigned int {
        float m2v[25], m4v[23], m8v[19];
        #pragma unroll
        for (int s = 0; s < 25; ++s) m2v[s] = fmaxf(a[7+s], a[8+s]);
        #pragma unroll
        for (int s = 0; s < 23; ++s) m4v[s] = fmaxf(m2v[s], m2v[s+2]);
        #pragma unroll
        for (int s = 0; s < 19; ++s) m8v[s] = fmaxf(m4v[s], m4v[s+4]);
        unsigned int wb = 0;
        #pragma unroll
        for (int e = 0; e < EL; ++e) {
            if (ud & (1u << e)) {
                float v = a[16+e];
                float wl = fmaxf(m8v[e], a[15+e]);      // max act [i-9, i-1]
                float wr = fmaxf(m8v[10+e], a[25+e]);   // max act [i+1, i+9]
                if (wl < v && wr <= v) wb |= (1u << e); // left tie beats, right tie loses
            }
        }
        return wb;
    };

    // binary dilation by +-9 (radius steps 1,2,3,3)
    auto dilate9 = [](unsigned long long m) -> unsigned long long {
        m |= (m << 1) | (m >> 1);
        m |= (m << 2) | (m >> 2);
        m |= (m << 3) | (m >> 3);
        m |= (m << 3) | (m >> 3);
        return m;
    };

    // ---- 5. ASYNC suppression (== scipy highest-first greedy).
    //      Published words = cumulative kept masks (monotone -> stale reads
    //      sound, verified R9). First LVLS-1 iterations also build one table
    //      level each (T hidden under S); then barrier-free tail.
    //      Termination: wave-ballot -> per-wave flags (no atomic contention).
    {
        volatile unsigned int* nkv = nk32 + 3;
        unsigned long long lastV = 0;
        int lvl = 1;
        int guard = 0;
        if (undec) {                       // initial local wins (0 exchanges)
            unsigned int wb = compute_wins(undec);
            if (wb) { kept |= wb; undec = 0; nkv[t] = kept; }
        }
        while (true) {
            if (undec) {
                unsigned long long V = 0;  // bit b = published winner at pos base-24+b
                #pragma unroll
                for (int q = 0; q < 7; ++q)
                    V |= ((unsigned long long)(nkv[t - 3 + q] & 0xFFu)) << (8 * q);
                if (V != lastV) {
                    lastV = V;
                    unsigned long long D = dilate9(V);
                    #pragma unroll
                    for (int s = 0; s < 40; ++s)            // slot s = pos base-16+s
                        if ((D >> (s + 8)) & 1ULL) a[s] = -1e30f;
                    #pragma unroll
                    for (int e = 0; e < EL; ++e)            // own elem = bit 24+e
                        if (undec & (1u << e))
                            if ((D >> (24 + e)) & 1ULL) undec &= ~(1u << e);
                    if (undec) {
                        unsigned int wb = compute_wins(undec);
                        if (wb) { kept |= wb; undec = 0; nkv[t] = kept; }
                    }
                }
            }
            if (lvl < LVLS) {              // paced table build (barriered rounds)
                const int h = 1 << lvl;
                #pragma unroll
                for (int j = 0; j < EL; ++j) {
                    int i = t + j * NT;
                    bool inb = (i + h < N);
                    float bx = inb ? TMX[lvl-1][i+h] : -3e38f;
                    float bn = inb ? TMN[lvl-1][i+h] : 3e38f;
                    cx[j] = fmaxf(cx[j], bx);
                    cn[j] = fminf(cn[j], bn);
                    TMX[lvl][i] = cx[j];
                    TMN[lvl][i] = cn[j];
                }
                ++lvl;
                __syncthreads();
                continue;                  // no termination check until tables done
            }
            bool mydone = (undec == 0);
            unsigned long long bal = __ballot(mydone);
            if (bal == ~0ULL && ln == 0) ((volatile int*)wdone)[wv] = 1;
            volatile int* wd = (volatile int*)wdone;
            int d0 = wd[0], d1 = wd[1], d2 = wd[2], d3 = wd[3];
            if (d0 & d1 & d2 & d3) break;
            if (mydone) __builtin_amdgcn_s_sleep(1);
            if (++guard > 65536) break;    // safety net (never expected)
        }
    }
    __syncthreads();

    // ---- 6. kept prefix compaction ----
    int myc = __popc(kept);
    int pre = myc;
    #pragma unroll
    for (int off = 1; off < 64; off <<= 1) {
        int up = __shfl_up(pre, off, 64);
        if (ln >= off) pre += up;
    }
    if (ln == 63) wtot[wv] = pre;
    __syncthreads();
    {
        int woff = 0;
        #pragma unroll
        for (int w = 0; w < 4; ++w) woff += (w < wv) ? wtot[w] : 0;
        int slot = woff + pre - myc;
        #pragma unroll
        for (int e = 0; e < EL; ++e)
            if (kept & (1u << e)) klist[slot++] = (unsigned short)(base + e);
    }
    const int ktot = wtot[0] + wtot[1] + wtot[2] + wtot[3];
    __syncthreads();

    // ---- 7. prominence: one peak/thread, L+R walks interleaved ----
    if (t < ktot) {
        const int i = klist[t];
        const float v = xs[i];
        const float* TX0 = &TMX[0][0];
        const float* TN0 = &TMN[0][0];
        int Lph = 0, Lp = i - 1, Lk = 0, Ls = 0;
        float Lm = v;
        if (Lp < 0) Lph = 2;
        int Rph = 0, Rp = i + 1, Rk = 0;
        float Rm = v;
        if (Rp >= N) Rph = 2;
        while (Lph != 2 || Rph != 2) {
            int lLev = 0, lIdx = 0, rLev = 0, rIdx = 0, Lrs = 0;
            if (Lph == 0) {
                int len = Lp + 1;
                Lk = (len >= (1 << LVLS)) ? LVLS : (31 - __clz(len));
                Ls = Lp + 1 - (1 << Lk);
                lLev = Lk - 1; lIdx = Ls;
            } else if (Lph == 1) {
                Lrs = Ls + (1 << (Lk - 1));
                lLev = Lk - 2; lIdx = Lrs;
            }
            if (Rph == 0) {
                int len = N - Rp;
                Rk = (len >= (1 << LVLS)) ? LVLS : (31 - __clz(len));
                rLev = Rk - 1; rIdx = Rp;
            } else if (Rph == 1) {
                rLev = Rk - 2; rIdx = Rp;
            }
            float lx = 0.0f, lnv = 0.0f, rx = 0.0f, rnv = 0.0f;
            if (Lph != 2) {   // both loads issue together (independent)
                const float* bX = (lLev < 0) ? xs : (TX0 + lLev * N);
                const float* bN = (lLev < 0) ? xs : (TN0 + lLev * N);
                lx = bX[lIdx]; lnv = bN[lIdx];
            }
            if (Rph != 2) {
                const float* bX = (rLev < 0) ? xs : (TX0 + rLev * N);
                const float* bN = (rLev < 0) ? xs : (TN0 + rLev * N);
                rx = bX[rIdx]; rnv = bN[rIdx];
            }
            if (Lph == 0) {
                if (lx > v) Lph = (Lk == 0) ? 2 : 1;
                else { Lm = fminf(Lm, lnv); Lp = Ls - 1; if (Lp < 0) Lph = 2; }
            } else if (Lph == 1) {
                if (lx > v) Ls = Lrs; else Lm = fminf(Lm, lnv);
                if (--Lk == 0) Lph = 2;
            }
            if (Rph == 0) {
                if (rx > v) Rph = (Rk == 0) ? 2 : 1;
                else { Rm = fminf(Rm, rnv); Rp += (1 << Rk); if (Rp >= N) Rph = 2; }
            } else if (Rph == 1) {
                if (!(rx > v)) { Rm = fminf(Rm, rnv); Rp += (1 << (Rk - 1)); }
                if (--Rk == 0) Rph = 2;
            }
        }
        if (v - fmaxf(Lm, Rm) >= PROMF) keepres[i] = 1;
    }
    __syncthreads();

    // ---- 8. output ----
    float res[EL];
    #pragma unroll
    for (int e = 0; e < EL; ++e) res[e] = keepres[base + e] ? 1.0f : 0.0f;
    float* outr = out + row * (size_t)N + base;
    ((float4*)outr)[0] = make_float4(res[0], res[1], res[2], res[3]);
    ((float4*)outr)[1] = make_float4(res[4], res[5], res[6], res[7]);
}

extern "C" void kernel_launch(void* const* d_in, const int* in_sizes, int n_in,
                              void* d_out, int out_size, void* d_ws, size_t ws_size,
                              hipStream_t stream) {
    const float* x = (const float*)d_in[0];
    float* outp = (float*)d_out;
    const int rows = in_sizes[0] / N;
    peak_kernel<<<rows, NT, 0, stream>>>(x, outp);
}